// Round 8
// baseline (442.067 us; speedup 1.0000x reference)
//
#include <hip/hip_runtime.h>
#include <hip/hip_cooperative_groups.h>
#include <math.h>

namespace cg = cooperative_groups;

// (B, T, D, H, L) = (8, 512, 128, 128, 2). All fp32 I/O.
#define BB 8
#define TT 512
#define DD 128
#define HH 128
#define BT_ (BB * TT)                 // 4096
#define CL 32                         // C-scan chunk length
#define NCH 16                        // number of chunks (TT/CL)
static const size_t BTH = (size_t)BT_ * HH;  // 524288

// ws: act[0,6*BTH): q | k | ifpack | vopack ; hbuf = act+6*BTH
// cbuf = act+7*BTH (1024*16*128), abuf (+16K), segA/segBn (8-step n
// summaries, 64K each), denb (4096), nbufB (fallback, 16K). ~23 MB used.
// d_out: Wt [0,196608); consumed by both proj dispatches, then overwritten
// by the final scan output (stream-ordered, safe).

struct WArgs { const float* W[6]; };
struct BArgs { const float* b[6]; };

template <int CTRL>
__device__ __forceinline__ float dpp_add(float x) {
  int y = __builtin_amdgcn_update_dpp(0, __builtin_bit_cast(int, x), CTRL,
                                      0xF, 0xF, true);
  return x + __builtin_bit_cast(float, y);
}

// ---------------------------------------------------------------------------
// Transpose all 12 weight slabs: Wt[l*6+p][d][h] = W_p[l][h][d].
// ---------------------------------------------------------------------------
__global__ __launch_bounds__(256)
void transpose_w(WArgs w, float* __restrict__ Wt) {
  __shared__ float t[32][33];
  const int l = blockIdx.y / 6, p = blockIdx.y % 6;
  const float* src = w.W[p] + (size_t)l * HH * DD;
  float* dst = Wt + (size_t)blockIdx.y * HH * DD;
  const int ty0 = (blockIdx.x >> 2) * 32, tx0 = (blockIdx.x & 3) * 32;
  const int tx = threadIdx.x & 31, ty = threadIdx.x >> 5;
#pragma unroll
  for (int j = 0; j < 32; j += 8)
    t[ty + j][tx] = src[(size_t)(ty0 + ty + j) * DD + tx0 + tx];
  __syncthreads();
#pragma unroll
  for (int j = 0; j < 32; j += 8)
    dst[(size_t)(tx0 + ty + j) * HH + ty0 + tx] = t[tx][ty + j];
}

// ---------------------------------------------------------------------------
// Projection (proven): grid (BT_/32, 6), block 256. Thread = 2 rows x 8 h.
// ---------------------------------------------------------------------------
__global__ __launch_bounds__(256)
void proj_kernel(const float* __restrict__ X, const float* __restrict__ Wtl,
                 BArgs args, float* __restrict__ act) {
  __shared__ float xs[32][132];
  const int p = blockIdx.y;
  const int row0 = blockIdx.x * 32;
  const int tid = threadIdx.x;
  {
    const float4* xg = (const float4*)(X + (size_t)row0 * DD);
#pragma unroll
    for (int i = 0; i < 4; ++i) {
      int u = tid + 256 * i;
      float4 v = xg[u];
      *(float4*)&xs[u >> 5][(u & 31) * 4] = v;
    }
  }
  __syncthreads();

  const int h0 = (tid & 15) * 8;
  const int r0 = (tid >> 4) * 2;
  const float* wtp = Wtl + (size_t)p * HH * DD;

  float acc[2][8];
#pragma unroll
  for (int r = 0; r < 2; ++r)
#pragma unroll
    for (int j = 0; j < 8; ++j) acc[r][j] = 0.f;

  for (int d0 = 0; d0 < DD; d0 += 4) {
    float4 wa[4], wb[4];
#pragma unroll
    for (int i = 0; i < 4; ++i) {
      wa[i] = *(const float4*)(wtp + (size_t)(d0 + i) * HH + h0);
      wb[i] = *(const float4*)(wtp + (size_t)(d0 + i) * HH + h0 + 4);
    }
    float4 x0 = *(const float4*)&xs[r0][d0];
    float4 x1 = *(const float4*)&xs[r0 + 1][d0];
    const float xa[4] = {x0.x, x0.y, x0.z, x0.w};
    const float xb[4] = {x1.x, x1.y, x1.z, x1.w};
#pragma unroll
    for (int i = 0; i < 4; ++i) {
      acc[0][0] = fmaf(xa[i], wa[i].x, acc[0][0]);
      acc[0][1] = fmaf(xa[i], wa[i].y, acc[0][1]);
      acc[0][2] = fmaf(xa[i], wa[i].z, acc[0][2]);
      acc[0][3] = fmaf(xa[i], wa[i].w, acc[0][3]);
      acc[0][4] = fmaf(xa[i], wb[i].x, acc[0][4]);
      acc[0][5] = fmaf(xa[i], wb[i].y, acc[0][5]);
      acc[0][6] = fmaf(xa[i], wb[i].z, acc[0][6]);
      acc[0][7] = fmaf(xa[i], wb[i].w, acc[0][7]);
      acc[1][0] = fmaf(xb[i], wa[i].x, acc[1][0]);
      acc[1][1] = fmaf(xb[i], wa[i].y, acc[1][1]);
      acc[1][2] = fmaf(xb[i], wa[i].z, acc[1][2]);
      acc[1][3] = fmaf(xb[i], wa[i].w, acc[1][3]);
      acc[1][4] = fmaf(xb[i], wb[i].x, acc[1][4]);
      acc[1][5] = fmaf(xb[i], wb[i].y, acc[1][5]);
      acc[1][6] = fmaf(xb[i], wb[i].z, acc[1][6]);
      acc[1][7] = fmaf(xb[i], wb[i].w, acc[1][7]);
    }
  }

  const float4 b0 = *(const float4*)(args.b[p] + h0);
  const float4 b1 = *(const float4*)(args.b[p] + h0 + 4);
  const float bias[8] = {b0.x, b0.y, b0.z, b0.w, b1.x, b1.y, b1.z, b1.w};
#pragma unroll
  for (int r = 0; r < 2; ++r) {
    const size_t row = (size_t)row0 + r0 + r;
    float v[8];
#pragma unroll
    for (int j = 0; j < 8; ++j) {
      float a = acc[r][j] + bias[j];
      if (p == 1)      a *= 0.088388347648318447f;   // 1/sqrt(128)
      else if (p == 3) a = __expf(a);
      else if (p >= 4) a = 1.0f / (1.0f + __expf(-a));
      v[j] = a;
    }
    if (p == 0) {
      float* dst = act + row * HH + h0;
      *(float4*)dst = make_float4(v[0], v[1], v[2], v[3]);
      *(float4*)(dst + 4) = make_float4(v[4], v[5], v[6], v[7]);
    } else if (p == 1) {
      float* dst = act + BTH + row * HH + h0;
      *(float4*)dst = make_float4(v[0], v[1], v[2], v[3]);
      *(float4*)(dst + 4) = make_float4(v[4], v[5], v[6], v[7]);
    } else if (p == 3 || p == 4) {       // i -> slot 0, f -> slot 1
      float* dst = act + 2 * BTH + row * 2 * HH + 2 * h0 + (p == 3 ? 0 : 1);
#pragma unroll
      for (int j = 0; j < 8; ++j) dst[2 * j] = v[j];
    } else {                             // v -> slot 0, o -> slot 1
      float* dst = act + 4 * BTH + row * 2 * HH + 2 * h0 + (p == 2 ? 0 : 1);
#pragma unroll
      for (int j = 0; j < 8; ++j) dst[2 * j] = v[j];
    }
  }
}

// ---------------------------------------------------------------------------
// scanfused (cooperative): phases A (chunk summaries) -> B (denominators) ->
// C (replay + h), with grid.sync between. Block (b, ch, qtr) stages q/k/gate
// tiles ONCE in phase A and reuses them in phase C. Phase B remaps blocks to
// (b, seg-of-8t): 8x64 = 512. 2 blocks/CU co-resident (launch_bounds 512,4;
// 52.5 KB LDS).
// ---------------------------------------------------------------------------
__global__ __launch_bounds__(512, 4)
void scanfused_kernel(const float* __restrict__ act, float* __restrict__ hout,
                      float* __restrict__ cbuf, float* __restrict__ abuf,
                      float* __restrict__ segA, float* __restrict__ segBn,
                      float* __restrict__ denb) {
  __shared__ __align__(16) float qt[CL][128];   // 16 KB
  __shared__ __align__(16) float kt[CL][128];   // 16 KB
  __shared__ __align__(16) float ift[CL][64];   // 8 KB
  __shared__ __align__(16) float vot[CL][64];   // 8 KB
  __shared__ float plds[8][132];                // 4.2 KB (phase B)
  __shared__ float dlds[CL];
  cg::grid_group grid = cg::this_grid();

  const int tid = threadIdx.x;
  const int lane = tid & 63, wid = tid >> 6;
  const int blk = blockIdx.x;
  const int b = blk & 7, ch = (blk >> 3) & (NCH - 1), qtr = blk >> 7;
  const int t0 = ch * CL;
  const int p0 = qtr * 32;
  const size_t boff = (size_t)b * TT * HH;
  const float* qg = act + boff;
  const float* kg = act + BTH + boff;
  const float* ifg = act + 2 * BTH + 2 * boff;
  const float* vog = act + 4 * BTH + 2 * boff;

  // ---- phase A: stage tiles; chunk C-summaries + 8-step n-summaries ----
#pragma unroll
  for (int i = 0; i < CL / 16; ++i) {
    const int u = tid + 512 * i;
    const int r = u >> 5, c = (u & 31) * 4;
    *(float4*)&qt[r][c] = *(const float4*)(qg + (size_t)(t0 + r) * HH + c);
    *(float4*)&kt[r][c] = *(const float4*)(kg + (size_t)(t0 + r) * HH + c);
  }
  {
    const int r = tid >> 4, c = (tid & 15) * 4;
    *(float4*)&ift[r][c] =
        *(const float4*)(ifg + (size_t)(t0 + r) * 2 * HH + 2 * p0 + c);
    *(float4*)&vot[r][c] =
        *(const float4*)(vog + (size_t)(t0 + r) * 2 * HH + 2 * p0 + c);
  }
  __syncthreads();

  const int pl = lane >> 4, cl = lane & 15;
  const int plocal = wid * 4 + pl;
  const int p = p0 + plocal;

  {
    float C[8];
#pragma unroll
    for (int j = 0; j < 8; ++j) C[j] = 0.f;
    float Af = 1.f, Aw = 1.f, Bw = 0.f;
#pragma unroll 4
    for (int t = 0; t < CL; ++t) {
      const float2 gif = *(const float2*)&ift[t][2 * plocal];
      const float2 gvo = *(const float2*)&vot[t][2 * plocal];
      const float4 k0 = *(const float4*)&kt[t][cl * 4];
      const float4 k1 = *(const float4*)&kt[t][cl * 4 + 64];
      const float kp = kt[t][p];                 // broadcast across cl
      const float a = gif.x * gvo.x;             // i*v
      const float f = gif.y;
      C[0] = fmaf(f, C[0], a * k0.x);
      C[1] = fmaf(f, C[1], a * k0.y);
      C[2] = fmaf(f, C[2], a * k0.z);
      C[3] = fmaf(f, C[3], a * k0.w);
      C[4] = fmaf(f, C[4], a * k1.x);
      C[5] = fmaf(f, C[5], a * k1.y);
      C[6] = fmaf(f, C[6], a * k1.z);
      C[7] = fmaf(f, C[7], a * k1.w);
      Af *= f;
      Aw *= f;
      Bw = fmaf(f, Bw, gif.x * kp);              // 8-step n-summary
      if ((t & 7) == 7) {
        if (cl == 0) {
          const size_t ss = ((size_t)(b * 64) + ch * 4 + (t >> 3)) * 128 + p;
          segA[ss] = Aw;
          segBn[ss] = Bw;
        }
        Aw = 1.f;
        Bw = 0.f;
      }
    }
    const size_t slot = (size_t)(b * 128 + p) * NCH + ch;
    *(float4*)(cbuf + slot * 128 + cl * 4) =
        make_float4(C[0], C[1], C[2], C[3]);
    *(float4*)(cbuf + slot * 128 + cl * 4 + 64) =
        make_float4(C[4], C[5], C[6], C[7]);
    if (cl == 0) abuf[slot] = Af;
  }

  grid.sync();

  // ---- phase B: denominators. Block -> (b2, seg of 8 t); tid<128 = p2. ----
  {
    const int b2 = blk & 7, seg = blk >> 3;      // 8 x 64 = 512
    const int tB0 = seg * 8;
    if (tid < 128) {
      const int p2 = tid;
      const size_t boff2 = (size_t)b2 * TT * HH;
      const float* qp2 = act + boff2 + p2;
      const float* kp2 = act + BTH + boff2 + p2;
      const float* ifp2 = act + 2 * BTH + 2 * boff2 + 2 * p2;
      const size_t sb = (size_t)(b2 * 64) * 128 + p2;
      float n = 0.f;                             // n at segment start
#pragma unroll 1
      for (int g = 0; g < seg; ++g)
        n = fmaf(segA[sb + (size_t)g * 128], n, segBn[sb + (size_t)g * 128]);
      float prod[8];
#pragma unroll
      for (int j = 0; j < 8; ++j) {
        const float2 iff = *(const float2*)(ifp2 + (size_t)(tB0 + j) * 2 * HH);
        const float kv = kp2[(size_t)(tB0 + j) * HH];
        const float qv = qp2[(size_t)(tB0 + j) * HH];
        prod[j] = n * qv;                        // OLD n (n_{t-1})
        n = fmaf(iff.y, n, iff.x * kv);
      }
#pragma unroll
      for (int j = 0; j < 8; ++j) plds[j][p2] = prod[j];
    }
    __syncthreads();
    if (tid < 128) {
      const int p2 = tid;
      const int j = p2 >> 4, c = p2 & 15;
      const float4 a = *(const float4*)&plds[j][c * 8];
      const float4 d = *(const float4*)&plds[j][c * 8 + 4];
      float s = ((a.x + a.y) + (a.z + a.w)) + ((d.x + d.y) + (d.z + d.w));
      s = dpp_add<0x111>(s);
      s = dpp_add<0x112>(s);
      s = dpp_add<0x114>(s);
      s = dpp_add<0x118>(s);                     // lane c==15 = full sum
      if ((p2 & 15) == 15)
        denb[(size_t)(b2 << 9) + tB0 + j] =
            __builtin_amdgcn_rcpf(fmaxf(fabsf(s), 1.0f));
    }
  }

  grid.sync();

  // ---- phase C: scale o by invden (in LDS), compose start-C, replay ----
  if (tid < CL) dlds[tid] = denb[(size_t)(b << 9) + t0 + tid];
  __syncthreads();
  {
    const int u = tid, u2 = tid + 512;           // 1024 (t, pp) elements
    vot[u >> 5][2 * (u & 31) + 1] *= dlds[u >> 5];
    vot[u2 >> 5][2 * (u2 & 31) + 1] *= dlds[u2 >> 5];
  }
  __syncthreads();
  {
    float C[8];
#pragma unroll
    for (int j = 0; j < 8; ++j) C[j] = 0.f;
    const size_t cb = (size_t)(b * 128 + p) * NCH;
#pragma unroll 1
    for (int g = 0; g < ch; ++g) {
      const float a = abuf[cb + g];
      const float4 b0 = *(const float4*)(cbuf + (cb + g) * 128 + cl * 4);
      const float4 b1 = *(const float4*)(cbuf + (cb + g) * 128 + cl * 4 + 64);
      C[0] = fmaf(a, C[0], b0.x);
      C[1] = fmaf(a, C[1], b0.y);
      C[2] = fmaf(a, C[2], b0.z);
      C[3] = fmaf(a, C[3], b0.w);
      C[4] = fmaf(a, C[4], b1.x);
      C[5] = fmaf(a, C[5], b1.y);
      C[6] = fmaf(a, C[6], b1.z);
      C[7] = fmaf(a, C[7], b1.w);
    }
    float* hbase = hout + boff + p;
#pragma unroll 4
    for (int t = 0; t < CL; ++t) {
      const float2 gif = *(const float2*)&ift[t][2 * plocal];
      const float2 gvo = *(const float2*)&vot[t][2 * plocal];
      const float4 q0 = *(const float4*)&qt[t][cl * 4];
      const float4 q1 = *(const float4*)&qt[t][cl * 4 + 64];
      const float4 k0 = *(const float4*)&kt[t][cl * 4];
      const float4 k1 = *(const float4*)&kt[t][cl * 4 + 64];
      float s0 = C[0] * q0.x;
      float s1 = C[4] * q1.x;
      s0 = fmaf(C[1], q0.y, s0);
      s1 = fmaf(C[5], q1.y, s1);
      s0 = fmaf(C[2], q0.z, s0);
      s1 = fmaf(C[6], q1.z, s1);
      s0 = fmaf(C[3], q0.w, s0);
      s1 = fmaf(C[7], q1.w, s1);
      float s = s0 + s1;
      const float a = gif.x * gvo.x;
      const float f = gif.y;
      C[0] = fmaf(f, C[0], a * k0.x);
      C[1] = fmaf(f, C[1], a * k0.y);
      C[2] = fmaf(f, C[2], a * k0.z);
      C[3] = fmaf(f, C[3], a * k0.w);
      C[4] = fmaf(f, C[4], a * k1.x);
      C[5] = fmaf(f, C[5], a * k1.y);
      C[6] = fmaf(f, C[6], a * k1.z);
      C[7] = fmaf(f, C[7], a * k1.w);
      s = dpp_add<0x111>(s);
      s = dpp_add<0x112>(s);
      s = dpp_add<0x114>(s);
      s = dpp_add<0x118>(s);
      if (cl == 15) hbase[(size_t)(t0 + t) * HH] = s * gvo.y;  // o*invden
    }
  }
}

// ---------------------------------------------------------------------------
// Fallback path (exact round-7 kernels) if cooperative launch is unavailable.
// ---------------------------------------------------------------------------
__global__ __launch_bounds__(512)
void cseg2_kernel(const float* __restrict__ act, float* __restrict__ cbuf,
                  float* __restrict__ abuf, float* __restrict__ nbufB) {
  __shared__ __align__(16) float kt[CL][128];
  __shared__ __align__(16) float ift[CL][64];
  __shared__ __align__(16) float vot[CL][64];
  const int tid = threadIdx.x;
  const int lane = tid & 63, wid = tid >> 6;
  const int blk = blockIdx.x;
  const int b = blk & 7, ch = (blk >> 3) & (NCH - 1), qtr = blk >> 7;
  const int t0 = ch * CL;
  const int p0 = qtr * 32;
  const size_t boff = (size_t)b * TT * HH;
  const float* kg = act + BTH + boff;
  const float* ifg = act + 2 * BTH + 2 * boff;
  const float* vog = act + 4 * BTH + 2 * boff;

#pragma unroll
  for (int i = 0; i < CL / 16; ++i) {
    const int u = tid + 512 * i;
    const int r = u >> 5, c = (u & 31) * 4;
    *(float4*)&kt[r][c] = *(const float4*)(kg + (size_t)(t0 + r) * HH + c);
  }
  {
    const int r = tid >> 4, c = (tid & 15) * 4;
    *(float4*)&ift[r][c] =
        *(const float4*)(ifg + (size_t)(t0 + r) * 2 * HH + 2 * p0 + c);
    *(float4*)&vot[r][c] =
        *(const float4*)(vog + (size_t)(t0 + r) * 2 * HH + 2 * p0 + c);
  }
  __syncthreads();

  const int pl = lane >> 4, cl = lane & 15;
  const int plocal = wid * 4 + pl;
  const int p = p0 + plocal;

  float C[8];
#pragma unroll
  for (int j = 0; j < 8; ++j) C[j] = 0.f;
  float Af = 1.f, Bn = 0.f;
#pragma unroll 4
  for (int t = 0; t < CL; ++t) {
    const float2 gif = *(const float2*)&ift[t][2 * plocal];
    const float2 gvo = *(const float2*)&vot[t][2 * plocal];
    const float4 k0 = *(const float4*)&kt[t][cl * 4];
    const float4 k1 = *(const float4*)&kt[t][cl * 4 + 64];
    const float kp = kt[t][p];
    const float a = gif.x * gvo.x;
    const float f = gif.y;
    C[0] = fmaf(f, C[0], a * k0.x);
    C[1] = fmaf(f, C[1], a * k0.y);
    C[2] = fmaf(f, C[2], a * k0.z);
    C[3] = fmaf(f, C[3], a * k0.w);
    C[4] = fmaf(f, C[4], a * k1.x);
    C[5] = fmaf(f, C[5], a * k1.y);
    C[6] = fmaf(f, C[6], a * k1.z);
    C[7] = fmaf(f, C[7], a * k1.w);
    Af *= f;
    Bn = fmaf(f, Bn, gif.x * kp);
  }
  const size_t slot = (size_t)(b * 128 + p) * NCH + ch;
  *(float4*)(cbuf + slot * 128 + cl * 4) = make_float4(C[0], C[1], C[2], C[3]);
  *(float4*)(cbuf + slot * 128 + cl * 4 + 64) =
      make_float4(C[4], C[5], C[6], C[7]);
  if (cl == 0) {
    abuf[slot] = Af;
    nbufB[slot] = Bn;
  }
}

__global__ __launch_bounds__(128)
void ndenom_kernel(float* __restrict__ act, const float* __restrict__ abuf,
                   const float* __restrict__ nbufB) {
  __shared__ float plds[8][132];
  __shared__ float den[8];
  const int b = blockIdx.x & 7, ch = blockIdx.x >> 3;
  const int p = threadIdx.x;
  const size_t boff = (size_t)b * TT * HH;
  const float* qp = act + boff + p;
  const float* kp = act + BTH + boff + p;
  const float* ifp = act + 2 * BTH + 2 * boff + 2 * p;
  float* vop = act + 4 * BTH + 2 * boff;
  const size_t cb = (size_t)(b * 128 + p) * NCH;

  float n = 0.f;
#pragma unroll 1
  for (int g = 0; g < ch; ++g) n = fmaf(abuf[cb + g], n, nbufB[cb + g]);

#pragma unroll 1
  for (int grp = 0; grp < CL / 8; ++grp) {
    const int t0 = ch * CL + grp * 8;
    float prod[8];
#pragma unroll
    for (int j = 0; j < 8; ++j) {
      const float2 iff = *(const float2*)(ifp + (size_t)(t0 + j) * 2 * HH);
      const float kv = kp[(size_t)(t0 + j) * HH];
      const float qv = qp[(size_t)(t0 + j) * HH];
      prod[j] = n * qv;
      n = fmaf(iff.y, n, iff.x * kv);
    }
#pragma unroll
    for (int j = 0; j < 8; ++j) plds[j][p] = prod[j];
    __syncthreads();
    {
      const int j = p >> 4, c = p & 15;
      const float4 a = *(const float4*)&plds[j][c * 8];
      const float4 d = *(const float4*)&plds[j][c * 8 + 4];
      float s = ((a.x + a.y) + (a.z + a.w)) + ((d.x + d.y) + (d.z + d.w));
      s = dpp_add<0x111>(s);
      s = dpp_add<0x112>(s);
      s = dpp_add<0x114>(s);
      s = dpp_add<0x118>(s);
      if ((p & 15) == 15)
        den[j] = __builtin_amdgcn_rcpf(fmaxf(fabsf(s), 1.0f));
    }
    __syncthreads();
#pragma unroll
    for (int j = 0; j < 8; ++j)
      vop[(size_t)(t0 + j) * 2 * HH + 2 * p + 1] *= den[j];
  }
}

__global__ __launch_bounds__(512)
void hscan2_kernel(const float* __restrict__ act, float* __restrict__ hout,
                   const float* __restrict__ cbuf,
                   const float* __restrict__ abuf) {
  __shared__ __align__(16) float qt[CL][128];
  __shared__ __align__(16) float kt[CL][128];
  __shared__ __align__(16) float ift[CL][64];
  __shared__ __align__(16) float vot[CL][64];
  const int tid = threadIdx.x;
  const int lane = tid & 63, wid = tid >> 6;
  const int blk = blockIdx.x;
  const int b = blk & 7, ch = (blk >> 3) & (NCH - 1), qtr = blk >> 7;
  const int t0 = ch * CL;
  const int p0 = qtr * 32;
  const size_t boff = (size_t)b * TT * HH;
  const float* qg = act + boff;
  const float* kg = act + BTH + boff;
  const float* ifg = act + 2 * BTH + 2 * boff;
  const float* vog = act + 4 * BTH + 2 * boff;

#pragma unroll
  for (int i = 0; i < CL / 16; ++i) {
    const int u = tid + 512 * i;
    const int r = u >> 5, c = (u & 31) * 4;
    *(float4*)&qt[r][c] = *(const float4*)(qg + (size_t)(t0 + r) * HH + c);
    *(float4*)&kt[r][c] = *(const float4*)(kg + (size_t)(t0 + r) * HH + c);
  }
  {
    const int r = tid >> 4, c = (tid & 15) * 4;
    *(float4*)&ift[r][c] =
        *(const float4*)(ifg + (size_t)(t0 + r) * 2 * HH + 2 * p0 + c);
    *(float4*)&vot[r][c] =
        *(const float4*)(vog + (size_t)(t0 + r) * 2 * HH + 2 * p0 + c);
  }
  __syncthreads();

  const int pl = lane >> 4, cl = lane & 15;
  const int plocal = wid * 4 + pl;
  const int p = p0 + plocal;

  float C[8];
#pragma unroll
  for (int j = 0; j < 8; ++j) C[j] = 0.f;
  {
    const size_t cb = (size_t)(b * 128 + p) * NCH;
#pragma unroll 1
    for (int g = 0; g < ch; ++g) {
      const float a = abuf[cb + g];
      const float4 b0 = *(const float4*)(cbuf + (cb + g) * 128 + cl * 4);
      const float4 b1 = *(const float4*)(cbuf + (cb + g) * 128 + cl * 4 + 64);
      C[0] = fmaf(a, C[0], b0.x);
      C[1] = fmaf(a, C[1], b0.y);
      C[2] = fmaf(a, C[2], b0.z);
      C[3] = fmaf(a, C[3], b0.w);
      C[4] = fmaf(a, C[4], b1.x);
      C[5] = fmaf(a, C[5], b1.y);
      C[6] = fmaf(a, C[6], b1.z);
      C[7] = fmaf(a, C[7], b1.w);
    }
  }
  float* hbase = hout + boff + p;

#pragma unroll 4
  for (int t = 0; t < CL; ++t) {
    const float2 gif = *(const float2*)&ift[t][2 * plocal];
    const float2 gvo = *(const float2*)&vot[t][2 * plocal];
    const float4 q0 = *(const float4*)&qt[t][cl * 4];
    const float4 q1 = *(const float4*)&qt[t][cl * 4 + 64];
    const float4 k0 = *(const float4*)&kt[t][cl * 4];
    const float4 k1 = *(const float4*)&kt[t][cl * 4 + 64];
    float s0 = C[0] * q0.x;
    float s1 = C[4] * q1.x;
    s0 = fmaf(C[1], q0.y, s0);
    s1 = fmaf(C[5], q1.y, s1);
    s0 = fmaf(C[2], q0.z, s0);
    s1 = fmaf(C[6], q1.z, s1);
    s0 = fmaf(C[3], q0.w, s0);
    s1 = fmaf(C[7], q1.w, s1);
    float s = s0 + s1;
    const float a = gif.x * gvo.x;
    const float f = gif.y;
    C[0] = fmaf(f, C[0], a * k0.x);
    C[1] = fmaf(f, C[1], a * k0.y);
    C[2] = fmaf(f, C[2], a * k0.z);
    C[3] = fmaf(f, C[3], a * k0.w);
    C[4] = fmaf(f, C[4], a * k1.x);
    C[5] = fmaf(f, C[5], a * k1.y);
    C[6] = fmaf(f, C[6], a * k1.z);
    C[7] = fmaf(f, C[7], a * k1.w);
    s = dpp_add<0x111>(s);
    s = dpp_add<0x112>(s);
    s = dpp_add<0x114>(s);
    s = dpp_add<0x118>(s);
    if (cl == 15) hbase[(size_t)(t0 + t) * HH] = s * gvo.y;
  }
}

// ---------------------------------------------------------------------------
extern "C" void kernel_launch(void* const* d_in, const int* in_sizes, int n_in,
                              void* d_out, int out_size, void* d_ws,
                              size_t ws_size, hipStream_t stream) {
  (void)in_sizes; (void)n_in; (void)out_size; (void)ws_size;
  const float* x = (const float*)d_in[0];
  float* act = (float*)d_ws;                     // 6 * BTH floats
  float* hbuf = act + 6 * BTH;                   // BTH floats (layer-1 h)
  float* cbuf = act + 7 * BTH;                   // 1024*NCH*128 (8 MB)
  float* abuf = cbuf + (size_t)1024 * NCH * 128; // 16K floats
  float* segA = abuf + (size_t)1024 * NCH;       // 8*64*128 = 64K floats
  float* segBn = segA + 65536;                   // 64K floats
  float* denb = segBn + 65536;                   // 4096 floats
  float* nbufB = denb + 4096;                    // 16K floats (fallback)
  float* Wt = (float*)d_out;                     // [0, 196608)

  WArgs wa;
  for (int j = 0; j < 6; ++j) wa.W[j] = (const float*)d_in[1 + j];
  transpose_w<<<dim3(16, 12), 256, 0, stream>>>(wa, Wt);

  for (int l = 0; l < 2; ++l) {
    BArgs ba;
    for (int j = 0; j < 6; ++j)
      ba.b[j] = (const float*)d_in[7 + j] + (size_t)l * HH;
    const float* wtl = Wt + (size_t)l * 6 * HH * DD;
    const float* xin = (l == 0) ? x : hbuf;
    float* hdst = (l == 0) ? hbuf : (float*)d_out;
    proj_kernel<<<dim3(BT_ / 32, 6), 256, 0, stream>>>(xin, wtl, ba, act);

    const float* actc = act;
    float* hd = hdst;
    void* kargs[] = {(void*)&actc, (void*)&hd,    (void*)&cbuf, (void*)&abuf,
                     (void*)&segA, (void*)&segBn, (void*)&denb};
    hipError_t e = hipLaunchCooperativeKernel(
        (const void*)&scanfused_kernel, dim3(512), dim3(512), kargs, 0,
        stream);
    if (e != hipSuccess) {
      // fallback: exact round-7 three-kernel path (parity, no regression)
      cseg2_kernel<<<512, 512, 0, stream>>>(act, cbuf, abuf, nbufB);
      ndenom_kernel<<<128, 128, 0, stream>>>(act, abuf, nbufB);
      hscan2_kernel<<<512, 512, 0, stream>>>(act, hdst, cbuf, abuf);
    }
  }
}

// Round 9
// 205.015 us; speedup vs baseline: 2.1563x; 2.1563x over previous
//
#include <hip/hip_runtime.h>
#include <math.h>

// (B, T, D, H, L) = (8, 512, 128, 128, 2). All fp32 I/O.
#define BB 8
#define TT 512
#define DD 128
#define HH 128
#define BT_ (BB * TT)                 // 4096
#define CL 32                         // C-scan chunk length
#define NCH 16                        // number of chunks (TT/CL)
static const size_t BTH = (size_t)BT_ * HH;  // 524288

// ws layout: act planes [0,6*BTH) : q | k | ifpack(2*BTH) | vopack(2*BTH)
//   q:      act + 0      [row][h]
//   k:      act + BTH    [row][h]     (pre-scaled by 1/sqrt(H) in proj)
//   ifpack: act + 2*BTH  [row][2h+{0:i,1:f}]
//   vopack: act + 4*BTH  [row][2h+{0:v,1:o}]  (o *= invden in ndenom)
// hbuf = act + 6*BTH (layer-1 output).
// cbuf = act + 7*BTH: raw C-chunk summaries (1024 chains x 16 x 128 = 8 MB)
// abuf = cbuf + 1024*NCH*128: per-chunk A = prod f   (16K floats)
// nbufB = abuf + 1024*NCH:    per-chunk n-summary B  (16K floats)
// d_out: Wt [0,196608) transposed weights; consumed by both proj dispatches,
// then overwritten by the final hscan2 output (stream-ordered, safe).

struct WArgs { const float* W[6]; };
struct BArgs { const float* b[6]; };

template <int CTRL>
__device__ __forceinline__ float dpp_add(float x) {
  int y = __builtin_amdgcn_update_dpp(0, __builtin_bit_cast(int, x), CTRL,
                                      0xF, 0xF, true);
  return x + __builtin_bit_cast(float, y);
}

// ---------------------------------------------------------------------------
// Transpose all 12 weight slabs: Wt[l*6+p][d][h] = W_p[l][h][d].
// ---------------------------------------------------------------------------
__global__ __launch_bounds__(256)
void transpose_w(WArgs w, float* __restrict__ Wt) {
  __shared__ float t[32][33];
  const int l = blockIdx.y / 6, p = blockIdx.y % 6;
  const float* src = w.W[p] + (size_t)l * HH * DD;
  float* dst = Wt + (size_t)blockIdx.y * HH * DD;
  const int ty0 = (blockIdx.x >> 2) * 32, tx0 = (blockIdx.x & 3) * 32;
  const int tx = threadIdx.x & 31, ty = threadIdx.x >> 5;
#pragma unroll
  for (int j = 0; j < 32; j += 8)
    t[ty + j][tx] = src[(size_t)(ty0 + ty + j) * DD + tx0 + tx];
  __syncthreads();
#pragma unroll
  for (int j = 0; j < 32; j += 8)
    dst[(size_t)(tx0 + ty + j) * HH + ty0 + tx] = t[tx][ty + j];
}

// ---------------------------------------------------------------------------
// Projection v2: out[p][row][h] = act_p( sum_d X[row][d]*Wt_p[d][h] + b_p[h] )
// grid (BT_/64, 6), block 256. Thread = 4 rows x 8 h (64-row x 128-h tile).
// Same per-thread W-load count as v1 now serves 2x the outputs -> per-
// dispatch W instruction traffic halves (proj was VMEM-issue/L1-bound).
// Per-output summation order identical to v1 -> bitwise-same results.
// ---------------------------------------------------------------------------
__global__ __launch_bounds__(256)
void proj_kernel(const float* __restrict__ X, const float* __restrict__ Wtl,
                 BArgs args, float* __restrict__ act) {
  __shared__ float xs[64][132];
  const int p = blockIdx.y;
  const int row0 = blockIdx.x * 64;
  const int tid = threadIdx.x;
  {
    const float4* xg = (const float4*)(X + (size_t)row0 * DD);
#pragma unroll
    for (int i = 0; i < 8; ++i) {
      int u = tid + 256 * i;  // float4 index within 64x128 tile
      float4 v = xg[u];
      *(float4*)&xs[u >> 5][(u & 31) * 4] = v;
    }
  }
  __syncthreads();

  const int h0 = (tid & 15) * 8;
  const int r0 = (tid >> 4) * 4;
  const float* wtp = Wtl + (size_t)p * HH * DD;

  float acc[4][8];
#pragma unroll
  for (int r = 0; r < 4; ++r)
#pragma unroll
    for (int j = 0; j < 8; ++j) acc[r][j] = 0.f;

  for (int d0 = 0; d0 < DD; d0 += 4) {
    float4 wa[4], wb[4];
#pragma unroll
    for (int i = 0; i < 4; ++i) {
      wa[i] = *(const float4*)(wtp + (size_t)(d0 + i) * HH + h0);
      wb[i] = *(const float4*)(wtp + (size_t)(d0 + i) * HH + h0 + 4);
    }
    float4 xr[4];
#pragma unroll
    for (int r = 0; r < 4; ++r) xr[r] = *(const float4*)&xs[r0 + r][d0];
#pragma unroll
    for (int i = 0; i < 4; ++i) {
#pragma unroll
      for (int r = 0; r < 4; ++r) {
        const float xv = (i == 0) ? xr[r].x
                        : (i == 1) ? xr[r].y
                        : (i == 2) ? xr[r].z : xr[r].w;
        acc[r][0] = fmaf(xv, wa[i].x, acc[r][0]);
        acc[r][1] = fmaf(xv, wa[i].y, acc[r][1]);
        acc[r][2] = fmaf(xv, wa[i].z, acc[r][2]);
        acc[r][3] = fmaf(xv, wa[i].w, acc[r][3]);
        acc[r][4] = fmaf(xv, wb[i].x, acc[r][4]);
        acc[r][5] = fmaf(xv, wb[i].y, acc[r][5]);
        acc[r][6] = fmaf(xv, wb[i].z, acc[r][6]);
        acc[r][7] = fmaf(xv, wb[i].w, acc[r][7]);
      }
    }
  }

  const float4 b0 = *(const float4*)(args.b[p] + h0);
  const float4 b1 = *(const float4*)(args.b[p] + h0 + 4);
  const float bias[8] = {b0.x, b0.y, b0.z, b0.w, b1.x, b1.y, b1.z, b1.w};
#pragma unroll
  for (int r = 0; r < 4; ++r) {
    const size_t row = (size_t)row0 + r0 + r;
    float v[8];
#pragma unroll
    for (int j = 0; j < 8; ++j) {
      float a = acc[r][j] + bias[j];
      if (p == 1)      a *= 0.088388347648318447f;   // 1/sqrt(128)
      else if (p == 3) a = __expf(a);
      else if (p >= 4) a = 1.0f / (1.0f + __expf(-a));
      v[j] = a;
    }
    if (p == 0) {
      float* dst = act + row * HH + h0;
      *(float4*)dst = make_float4(v[0], v[1], v[2], v[3]);
      *(float4*)(dst + 4) = make_float4(v[4], v[5], v[6], v[7]);
    } else if (p == 1) {
      float* dst = act + BTH + row * HH + h0;
      *(float4*)dst = make_float4(v[0], v[1], v[2], v[3]);
      *(float4*)(dst + 4) = make_float4(v[4], v[5], v[6], v[7]);
    } else if (p == 3 || p == 4) {       // i -> slot 0, f -> slot 1
      float* dst = act + 2 * BTH + row * 2 * HH + 2 * h0 + (p == 3 ? 0 : 1);
#pragma unroll
      for (int j = 0; j < 8; ++j) dst[2 * j] = v[j];
    } else {                             // v -> slot 0, o -> slot 1
      float* dst = act + 4 * BTH + row * 2 * HH + 2 * h0 + (p == 2 ? 0 : 1);
#pragma unroll
      for (int j = 0; j < 8; ++j) dst[2 * j] = v[j];
    }
  }
}

// ---------------------------------------------------------------------------
// cseg2 (+fused n-summary): block-tiled chunk summaries. One 512-thread
// block per (b, chunk, p-quarter): grid 512 (2 blocks/CU). Block stages its
// k tile + 32-p gate slices into LDS once. Lane (pl=lane>>4, cl=lane&15)
// owns p-row = qtr*32 + wid*4 + pl, cols cl*4+{0..3}+{0,64}.
// Per t also advances the n-summary Bn = f*Bn + i*k[p] (LDS broadcast read);
// A = prod f is shared by C- and n-scans (same scalar). (proven, round 7)
// ---------------------------------------------------------------------------
__global__ __launch_bounds__(512)
void cseg2_kernel(const float* __restrict__ act, float* __restrict__ cbuf,
                  float* __restrict__ abuf, float* __restrict__ nbufB) {
  __shared__ __align__(16) float kt[CL][128];
  __shared__ __align__(16) float ift[CL][64];
  __shared__ __align__(16) float vot[CL][64];
  const int tid = threadIdx.x;
  const int lane = tid & 63, wid = tid >> 6;
  const int blk = blockIdx.x;
  const int b = blk & 7, ch = (blk >> 3) & (NCH - 1), qtr = blk >> 7;
  const int t0 = ch * CL;
  const int p0 = qtr * 32;
  const size_t boff = (size_t)b * TT * HH;
  const float* kg = act + BTH + boff;
  const float* ifg = act + 2 * BTH + 2 * boff;
  const float* vog = act + 4 * BTH + 2 * boff;

#pragma unroll
  for (int i = 0; i < CL / 16; ++i) {
    const int u = tid + 512 * i;                 // f4 index
    const int r = u >> 5, c = (u & 31) * 4;
    *(float4*)&kt[r][c] = *(const float4*)(kg + (size_t)(t0 + r) * HH + c);
  }
  {
    const int r = tid >> 4, c = (tid & 15) * 4;  // 512 f4 = CL x 64
    *(float4*)&ift[r][c] =
        *(const float4*)(ifg + (size_t)(t0 + r) * 2 * HH + 2 * p0 + c);
    *(float4*)&vot[r][c] =
        *(const float4*)(vog + (size_t)(t0 + r) * 2 * HH + 2 * p0 + c);
  }
  __syncthreads();

  const int pl = lane >> 4, cl = lane & 15;
  const int plocal = wid * 4 + pl;               // 0..31
  const int p = p0 + plocal;

  float C[8];
#pragma unroll
  for (int j = 0; j < 8; ++j) C[j] = 0.f;
  float Af = 1.f, Bn = 0.f;

#pragma unroll 4
  for (int t = 0; t < CL; ++t) {
    const float2 gif = *(const float2*)&ift[t][2 * plocal];
    const float2 gvo = *(const float2*)&vot[t][2 * plocal];
    const float4 k0 = *(const float4*)&kt[t][cl * 4];
    const float4 k1 = *(const float4*)&kt[t][cl * 4 + 64];
    const float kp = kt[t][p];                   // broadcast across cl lanes
    const float a = gif.x * gvo.x;               // i*v
    const float f = gif.y;
    C[0] = fmaf(f, C[0], a * k0.x);
    C[1] = fmaf(f, C[1], a * k0.y);
    C[2] = fmaf(f, C[2], a * k0.z);
    C[3] = fmaf(f, C[3], a * k0.w);
    C[4] = fmaf(f, C[4], a * k1.x);
    C[5] = fmaf(f, C[5], a * k1.y);
    C[6] = fmaf(f, C[6], a * k1.z);
    C[7] = fmaf(f, C[7], a * k1.w);
    Af *= f;
    Bn = fmaf(f, Bn, gif.x * kp);                // n-summary
  }

  const size_t slot = (size_t)(b * 128 + p) * NCH + ch;
  *(float4*)(cbuf + slot * 128 + cl * 4) = make_float4(C[0], C[1], C[2], C[3]);
  *(float4*)(cbuf + slot * 128 + cl * 4 + 64) =
      make_float4(C[4], C[5], C[6], C[7]);
  if (cl == 0) {
    abuf[slot] = Af;
    nbufB[slot] = Bn;
  }
}

// ---------------------------------------------------------------------------
// ndenom: per (b, chunk) block of 128 threads (p). Inline prefix-compose of
// the <=15 prior n-chunk summaries, then replay the 32 steps in 8-t groups
// with the proven LDS-transpose denominator reduce; scale o in place.
// grid 128 (b = blk&7, ch = blk>>3). (proven, round 7)
// ---------------------------------------------------------------------------
__global__ __launch_bounds__(128)
void ndenom_kernel(float* __restrict__ act, const float* __restrict__ abuf,
                   const float* __restrict__ nbufB) {
  __shared__ float plds[8][132];
  __shared__ float den[8];
  const int b = blockIdx.x & 7, ch = blockIdx.x >> 3;
  const int p = threadIdx.x;
  const size_t boff = (size_t)b * TT * HH;
  const float* qp = act + boff + p;
  const float* kp = act + BTH + boff + p;
  const float* ifp = act + 2 * BTH + 2 * boff + 2 * p;
  float* vop = act + 4 * BTH + 2 * boff;
  const size_t cb = (size_t)(b * 128 + p) * NCH;

  float n = 0.f;                        // n at chunk start
#pragma unroll 1
  for (int g = 0; g < ch; ++g) n = fmaf(abuf[cb + g], n, nbufB[cb + g]);

#pragma unroll 1
  for (int grp = 0; grp < CL / 8; ++grp) {
    const int t0 = ch * CL + grp * 8;
    float prod[8];
#pragma unroll
    for (int j = 0; j < 8; ++j) {
      const float2 iff = *(const float2*)(ifp + (size_t)(t0 + j) * 2 * HH);
      const float kv = kp[(size_t)(t0 + j) * HH];
      const float qv = qp[(size_t)(t0 + j) * HH];
      prod[j] = n * qv;                 // OLD n (n_{t-1})
      n = fmaf(iff.y, n, iff.x * kv);
    }
#pragma unroll
    for (int j = 0; j < 8; ++j) plds[j][p] = prod[j];
    __syncthreads();
    {
      const int j = p >> 4, c = p & 15; // 16 threads per t
      const float4 a = *(const float4*)&plds[j][c * 8];
      const float4 d = *(const float4*)&plds[j][c * 8 + 4];
      float s = ((a.x + a.y) + (a.z + a.w)) + ((d.x + d.y) + (d.z + d.w));
      s = dpp_add<0x111>(s);
      s = dpp_add<0x112>(s);
      s = dpp_add<0x114>(s);
      s = dpp_add<0x118>(s);            // lane 15 of each 16-row = full sum
      if ((p & 15) == 15)
        den[j] = __builtin_amdgcn_rcpf(fmaxf(fabsf(s), 1.0f));
    }
    __syncthreads();
#pragma unroll
    for (int j = 0; j < 8; ++j)
      vop[(size_t)(t0 + j) * 2 * HH + 2 * p + 1] *= den[j];
  }
}

// ---------------------------------------------------------------------------
// hscan2: replay chunk from inline-composed start-C with h output (proven
// block-tiled structure). grid 512 (b, ch, qtr), block 512. (round 7)
// ---------------------------------------------------------------------------
__global__ __launch_bounds__(512)
void hscan2_kernel(const float* __restrict__ act, float* __restrict__ hout,
                   const float* __restrict__ cbuf,
                   const float* __restrict__ abuf) {
  __shared__ __align__(16) float qt[CL][128];
  __shared__ __align__(16) float kt[CL][128];
  __shared__ __align__(16) float ift[CL][64];
  __shared__ __align__(16) float vot[CL][64];  // o pre-scaled by invden
  const int tid = threadIdx.x;
  const int lane = tid & 63, wid = tid >> 6;
  const int blk = blockIdx.x;
  const int b = blk & 7, ch = (blk >> 3) & (NCH - 1), qtr = blk >> 7;
  const int t0 = ch * CL;
  const int p0 = qtr * 32;
  const size_t boff = (size_t)b * TT * HH;
  const float* qg = act + boff;
  const float* kg = act + BTH + boff;
  const float* ifg = act + 2 * BTH + 2 * boff;
  const float* vog = act + 4 * BTH + 2 * boff;

#pragma unroll
  for (int i = 0; i < CL / 16; ++i) {
    const int u = tid + 512 * i;
    const int r = u >> 5, c = (u & 31) * 4;
    *(float4*)&qt[r][c] = *(const float4*)(qg + (size_t)(t0 + r) * HH + c);
    *(float4*)&kt[r][c] = *(const float4*)(kg + (size_t)(t0 + r) * HH + c);
  }
  {
    const int r = tid >> 4, c = (tid & 15) * 4;
    *(float4*)&ift[r][c] =
        *(const float4*)(ifg + (size_t)(t0 + r) * 2 * HH + 2 * p0 + c);
    *(float4*)&vot[r][c] =
        *(const float4*)(vog + (size_t)(t0 + r) * 2 * HH + 2 * p0 + c);
  }
  __syncthreads();

  const int pl = lane >> 4, cl = lane & 15;
  const int plocal = wid * 4 + pl;
  const int p = p0 + plocal;

  // start-C: inline compose of prior chunk summaries (Cs = A_g*Cs + B_g)
  float C[8];
#pragma unroll
  for (int j = 0; j < 8; ++j) C[j] = 0.f;
  {
    const size_t cb = (size_t)(b * 128 + p) * NCH;
#pragma unroll 1
    for (int g = 0; g < ch; ++g) {
      const float a = abuf[cb + g];
      const float4 b0 = *(const float4*)(cbuf + (cb + g) * 128 + cl * 4);
      const float4 b1 = *(const float4*)(cbuf + (cb + g) * 128 + cl * 4 + 64);
      C[0] = fmaf(a, C[0], b0.x);
      C[1] = fmaf(a, C[1], b0.y);
      C[2] = fmaf(a, C[2], b0.z);
      C[3] = fmaf(a, C[3], b0.w);
      C[4] = fmaf(a, C[4], b1.x);
      C[5] = fmaf(a, C[5], b1.y);
      C[6] = fmaf(a, C[6], b1.z);
      C[7] = fmaf(a, C[7], b1.w);
    }
  }
  float* hbase = hout + boff + p;

#pragma unroll 4
  for (int t = 0; t < CL; ++t) {
    const float2 gif = *(const float2*)&ift[t][2 * plocal];
    const float2 gvo = *(const float2*)&vot[t][2 * plocal];
    const float4 q0 = *(const float4*)&qt[t][cl * 4];
    const float4 q1 = *(const float4*)&qt[t][cl * 4 + 64];
    const float4 k0 = *(const float4*)&kt[t][cl * 4];
    const float4 k1 = *(const float4*)&kt[t][cl * 4 + 64];
    // h-tilde partial from OLD C
    float s0 = C[0] * q0.x;
    float s1 = C[4] * q1.x;
    s0 = fmaf(C[1], q0.y, s0);
    s1 = fmaf(C[5], q1.y, s1);
    s0 = fmaf(C[2], q0.z, s0);
    s1 = fmaf(C[6], q1.z, s1);
    s0 = fmaf(C[3], q0.w, s0);
    s1 = fmaf(C[7], q1.w, s1);
    float s = s0 + s1;
    // C update
    const float a = gif.x * gvo.x;               // i*v
    const float f = gif.y;
    C[0] = fmaf(f, C[0], a * k0.x);
    C[1] = fmaf(f, C[1], a * k0.y);
    C[2] = fmaf(f, C[2], a * k0.z);
    C[3] = fmaf(f, C[3], a * k0.w);
    C[4] = fmaf(f, C[4], a * k1.x);
    C[5] = fmaf(f, C[5], a * k1.y);
    C[6] = fmaf(f, C[6], a * k1.z);
    C[7] = fmaf(f, C[7], a * k1.w);
    // reduce over the 16-lane row: lane cl==15 holds the full col-sum
    s = dpp_add<0x111>(s);
    s = dpp_add<0x112>(s);
    s = dpp_add<0x114>(s);
    s = dpp_add<0x118>(s);
    if (cl == 15) hbase[(size_t)(t0 + t) * HH] = s * gvo.y;  // o' = o*invden
  }
}

// ---------------------------------------------------------------------------
extern "C" void kernel_launch(void* const* d_in, const int* in_sizes, int n_in,
                              void* d_out, int out_size, void* d_ws,
                              size_t ws_size, hipStream_t stream) {
  (void)in_sizes; (void)n_in; (void)out_size; (void)ws_size;
  const float* x = (const float*)d_in[0];
  float* act = (float*)d_ws;                     // 6 * BTH floats
  float* hbuf = act + 6 * BTH;                   // BTH floats (layer-1 h)
  float* cbuf = act + 7 * BTH;                   // 1024*NCH*128 floats (8 MB)
  float* abuf = cbuf + (size_t)1024 * NCH * 128; // 16K floats
  float* nbufB = abuf + (size_t)1024 * NCH;      // 16K floats
  float* Wt = (float*)d_out;                     // [0, 196608)

  WArgs wa;
  for (int j = 0; j < 6; ++j) wa.W[j] = (const float*)d_in[1 + j];
  transpose_w<<<dim3(16, 12), 256, 0, stream>>>(wa, Wt);

  for (int l = 0; l < 2; ++l) {
    BArgs ba;
    for (int j = 0; j < 6; ++j)
      ba.b[j] = (const float*)d_in[7 + j] + (size_t)l * HH;
    const float* wtl = Wt + (size_t)l * 6 * HH * DD;
    const float* xin = (l == 0) ? x : hbuf;
    float* hdst = (l == 0) ? hbuf : (float*)d_out;
    proj_kernel<<<dim3(BT_ / 64, 6), 256, 0, stream>>>(xin, wtl, ba, act);
    cseg2_kernel<<<512, 512, 0, stream>>>(act, cbuf, abuf, nbufB);
    ndenom_kernel<<<128, 128, 0, stream>>>(act, abuf, nbufB);
    hscan2_kernel<<<512, 512, 0, stream>>>(act, hdst, cbuf, abuf);
  }
}

// Round 10
// 197.867 us; speedup vs baseline: 2.2342x; 1.0361x over previous
//
#include <hip/hip_runtime.h>
#include <math.h>

// (B, T, D, H, L) = (8, 512, 128, 128, 2). All fp32 I/O.
#define BB 8
#define TT 512
#define DD 128
#define HH 128
#define BT_ (BB * TT)                 // 4096
#define CL 32                         // C-scan chunk length
#define NCH 16                        // number of chunks (TT/CL)
static const size_t BTH = (size_t)BT_ * HH;  // 524288

// ws layout: act planes [0,6*BTH) : q | k | ifpack(2*BTH) | vopack(2*BTH)
//   q:      act + 0      [row][h]
//   k:      act + BTH    [row][h]     (pre-scaled by 1/sqrt(H) in proj)
//   ifpack: act + 2*BTH  [row][2h+{0:i,1:f}]
//   vopack: act + 4*BTH  [row][2h+{0:v,1:o}]  (o scaled in-LDS in hscan3)
// hbuf = act + 6*BTH (layer-1 output).
// cbuf  = act + 7*BTH: C-chunk summaries [(b*128+p)*NCH+ch][128]  (8 MB)
// abuf  = cbuf + 1024*NCH*128: chunk A=prod f,  layout [ch][b][p] (16K)
// nbufB = abuf + 16384:        chunk n-B,       layout [ch][b][p] (16K)
// segA8 = nbufB + 16384:       8-step n-A, [ch*4+s][b][p]         (64K)
// segB8 = segA8 + 65536:       8-step n-B, [ch*4+s][b][p]         (64K)
// d_out: Wt [0,196608) transposed weights; consumed by both proj dispatches,
// then overwritten by the final hscan3 output (stream-ordered, safe).

struct WArgs { const float* W[6]; };
struct BArgs { const float* b[6]; };

template <int CTRL>
__device__ __forceinline__ float dpp_add(float x) {
  int y = __builtin_amdgcn_update_dpp(0, __builtin_bit_cast(int, x), CTRL,
                                      0xF, 0xF, true);
  return x + __builtin_bit_cast(float, y);
}

// ---------------------------------------------------------------------------
// Transpose all 12 weight slabs: Wt[l*6+p][d][h] = W_p[l][h][d].
// ---------------------------------------------------------------------------
__global__ __launch_bounds__(256)
void transpose_w(WArgs w, float* __restrict__ Wt) {
  __shared__ float t[32][33];
  const int l = blockIdx.y / 6, p = blockIdx.y % 6;
  const float* src = w.W[p] + (size_t)l * HH * DD;
  float* dst = Wt + (size_t)blockIdx.y * HH * DD;
  const int ty0 = (blockIdx.x >> 2) * 32, tx0 = (blockIdx.x & 3) * 32;
  const int tx = threadIdx.x & 31, ty = threadIdx.x >> 5;
#pragma unroll
  for (int j = 0; j < 32; j += 8)
    t[ty + j][tx] = src[(size_t)(ty0 + ty + j) * DD + tx0 + tx];
  __syncthreads();
#pragma unroll
  for (int j = 0; j < 32; j += 8)
    dst[(size_t)(tx0 + ty + j) * HH + ty0 + tx] = t[tx][ty + j];
}

// ---------------------------------------------------------------------------
// Projection v2 (proven round 9): grid (BT_/64, 6), block 256.
// Thread = 4 rows x 8 h (64-row x 128-h tile).
// ---------------------------------------------------------------------------
__global__ __launch_bounds__(256)
void proj_kernel(const float* __restrict__ X, const float* __restrict__ Wtl,
                 BArgs args, float* __restrict__ act) {
  __shared__ float xs[64][132];
  const int p = blockIdx.y;
  const int row0 = blockIdx.x * 64;
  const int tid = threadIdx.x;
  {
    const float4* xg = (const float4*)(X + (size_t)row0 * DD);
#pragma unroll
    for (int i = 0; i < 8; ++i) {
      int u = tid + 256 * i;  // float4 index within 64x128 tile
      float4 v = xg[u];
      *(float4*)&xs[u >> 5][(u & 31) * 4] = v;
    }
  }
  __syncthreads();

  const int h0 = (tid & 15) * 8;
  const int r0 = (tid >> 4) * 4;
  const float* wtp = Wtl + (size_t)p * HH * DD;

  float acc[4][8];
#pragma unroll
  for (int r = 0; r < 4; ++r)
#pragma unroll
    for (int j = 0; j < 8; ++j) acc[r][j] = 0.f;

  for (int d0 = 0; d0 < DD; d0 += 4) {
    float4 wa[4], wb[4];
#pragma unroll
    for (int i = 0; i < 4; ++i) {
      wa[i] = *(const float4*)(wtp + (size_t)(d0 + i) * HH + h0);
      wb[i] = *(const float4*)(wtp + (size_t)(d0 + i) * HH + h0 + 4);
    }
    float4 xr[4];
#pragma unroll
    for (int r = 0; r < 4; ++r) xr[r] = *(const float4*)&xs[r0 + r][d0];
#pragma unroll
    for (int i = 0; i < 4; ++i) {
#pragma unroll
      for (int r = 0; r < 4; ++r) {
        const float xv = (i == 0) ? xr[r].x
                        : (i == 1) ? xr[r].y
                        : (i == 2) ? xr[r].z : xr[r].w;
        acc[r][0] = fmaf(xv, wa[i].x, acc[r][0]);
        acc[r][1] = fmaf(xv, wa[i].y, acc[r][1]);
        acc[r][2] = fmaf(xv, wa[i].z, acc[r][2]);
        acc[r][3] = fmaf(xv, wa[i].w, acc[r][3]);
        acc[r][4] = fmaf(xv, wb[i].x, acc[r][4]);
        acc[r][5] = fmaf(xv, wb[i].y, acc[r][5]);
        acc[r][6] = fmaf(xv, wb[i].z, acc[r][6]);
        acc[r][7] = fmaf(xv, wb[i].w, acc[r][7]);
      }
    }
  }

  const float4 b0 = *(const float4*)(args.b[p] + h0);
  const float4 b1 = *(const float4*)(args.b[p] + h0 + 4);
  const float bias[8] = {b0.x, b0.y, b0.z, b0.w, b1.x, b1.y, b1.z, b1.w};
#pragma unroll
  for (int r = 0; r < 4; ++r) {
    const size_t row = (size_t)row0 + r0 + r;
    float v[8];
#pragma unroll
    for (int j = 0; j < 8; ++j) {
      float a = acc[r][j] + bias[j];
      if (p == 1)      a *= 0.088388347648318447f;   // 1/sqrt(128)
      else if (p == 3) a = __expf(a);
      else if (p >= 4) a = 1.0f / (1.0f + __expf(-a));
      v[j] = a;
    }
    if (p == 0) {
      float* dst = act + row * HH + h0;
      *(float4*)dst = make_float4(v[0], v[1], v[2], v[3]);
      *(float4*)(dst + 4) = make_float4(v[4], v[5], v[6], v[7]);
    } else if (p == 1) {
      float* dst = act + BTH + row * HH + h0;
      *(float4*)dst = make_float4(v[0], v[1], v[2], v[3]);
      *(float4*)(dst + 4) = make_float4(v[4], v[5], v[6], v[7]);
    } else if (p == 3 || p == 4) {       // i -> slot 0, f -> slot 1
      float* dst = act + 2 * BTH + row * 2 * HH + 2 * h0 + (p == 3 ? 0 : 1);
#pragma unroll
      for (int j = 0; j < 8; ++j) dst[2 * j] = v[j];
    } else {                             // v -> slot 0, o -> slot 1
      float* dst = act + 4 * BTH + row * 2 * HH + 2 * h0 + (p == 2 ? 0 : 1);
#pragma unroll
      for (int j = 0; j < 8; ++j) dst[2 * j] = v[j];
    }
  }
}

// ---------------------------------------------------------------------------
// cseg2: block-tiled chunk summaries (proven round 7) + 8-step n-summaries
// (proven round 8 phase A). grid 512 (b, ch, qtr), block 512.
// ---------------------------------------------------------------------------
__global__ __launch_bounds__(512)
void cseg2_kernel(const float* __restrict__ act, float* __restrict__ cbuf,
                  float* __restrict__ abuf, float* __restrict__ nbufB,
                  float* __restrict__ segA8, float* __restrict__ segB8) {
  __shared__ __align__(16) float kt[CL][128];
  __shared__ __align__(16) float ift[CL][64];
  __shared__ __align__(16) float vot[CL][64];
  const int tid = threadIdx.x;
  const int lane = tid & 63, wid = tid >> 6;
  const int blk = blockIdx.x;
  const int b = blk & 7, ch = (blk >> 3) & (NCH - 1), qtr = blk >> 7;
  const int t0 = ch * CL;
  const int p0 = qtr * 32;
  const size_t boff = (size_t)b * TT * HH;
  const float* kg = act + BTH + boff;
  const float* ifg = act + 2 * BTH + 2 * boff;
  const float* vog = act + 4 * BTH + 2 * boff;

#pragma unroll
  for (int i = 0; i < CL / 16; ++i) {
    const int u = tid + 512 * i;                 // f4 index
    const int r = u >> 5, c = (u & 31) * 4;
    *(float4*)&kt[r][c] = *(const float4*)(kg + (size_t)(t0 + r) * HH + c);
  }
  {
    const int r = tid >> 4, c = (tid & 15) * 4;  // 512 f4 = CL x 64
    *(float4*)&ift[r][c] =
        *(const float4*)(ifg + (size_t)(t0 + r) * 2 * HH + 2 * p0 + c);
    *(float4*)&vot[r][c] =
        *(const float4*)(vog + (size_t)(t0 + r) * 2 * HH + 2 * p0 + c);
  }
  __syncthreads();

  const int pl = lane >> 4, cl = lane & 15;
  const int plocal = wid * 4 + pl;               // 0..31
  const int p = p0 + plocal;

  float C[8];
#pragma unroll
  for (int j = 0; j < 8; ++j) C[j] = 0.f;
  float Af = 1.f, Bn = 0.f, Aw = 1.f, Bw = 0.f;

#pragma unroll 4
  for (int t = 0; t < CL; ++t) {
    const float2 gif = *(const float2*)&ift[t][2 * plocal];
    const float2 gvo = *(const float2*)&vot[t][2 * plocal];
    const float4 k0 = *(const float4*)&kt[t][cl * 4];
    const float4 k1 = *(const float4*)&kt[t][cl * 4 + 64];
    const float kp = kt[t][p];                   // broadcast across cl lanes
    const float a = gif.x * gvo.x;               // i*v
    const float f = gif.y;
    C[0] = fmaf(f, C[0], a * k0.x);
    C[1] = fmaf(f, C[1], a * k0.y);
    C[2] = fmaf(f, C[2], a * k0.z);
    C[3] = fmaf(f, C[3], a * k0.w);
    C[4] = fmaf(f, C[4], a * k1.x);
    C[5] = fmaf(f, C[5], a * k1.y);
    C[6] = fmaf(f, C[6], a * k1.z);
    C[7] = fmaf(f, C[7], a * k1.w);
    Af *= f;
    Bn = fmaf(f, Bn, gif.x * kp);                // chunk n-summary
    Aw *= f;
    Bw = fmaf(f, Bw, gif.x * kp);                // 8-step n-summary
    if ((t & 7) == 7) {
      if (cl == 0) {
        const size_t si = (size_t)(ch * 4 + (t >> 3)) * 1024 + b * 128 + p;
        segA8[si] = Aw;
        segB8[si] = Bw;
      }
      Aw = 1.f;
      Bw = 0.f;
    }
  }

  const size_t slot = (size_t)(b * 128 + p) * NCH + ch;
  *(float4*)(cbuf + slot * 128 + cl * 4) = make_float4(C[0], C[1], C[2], C[3]);
  *(float4*)(cbuf + slot * 128 + cl * 4 + 64) =
      make_float4(C[4], C[5], C[6], C[7]);
  if (cl == 0) {
    const size_t ci = (size_t)ch * 1024 + b * 128 + p;
    abuf[ci] = Af;
    nbufB[ci] = Bn;
  }
}

// ---------------------------------------------------------------------------
// hscan3 = ndenom + hscan2 fused. grid 512 (b, ch, qtr), block 512.
// Stages q/k (full 128h) + i,f (ALL 128 p) + v,o (own qtr). Den phase:
// thread (seg = tid>>7, p = tid&127) composes its n-prefix from register-
// unrolled chunk summaries (<=15) + 8-step summaries (<=3), replays 8 steps
// from LDS, then full-wave 6-step DPP reduce (proven rounds 2-5) + cross-
// wave combine -> den[32]; o scaled in LDS; then round-7 replay verbatim.
// LDS 72.4 KB -> 2 blocks/CU.
// ---------------------------------------------------------------------------
__global__ __launch_bounds__(512)
void hscan3_kernel(const float* __restrict__ act, float* __restrict__ hout,
                   const float* __restrict__ cbuf,
                   const float* __restrict__ abuf,
                   const float* __restrict__ nbufB,
                   const float* __restrict__ segA8,
                   const float* __restrict__ segB8) {
  __shared__ __align__(16) float qt[CL][128];    // 16 KB
  __shared__ __align__(16) float kt[CL][128];    // 16 KB
  __shared__ __align__(16) float iff[CL][256];   // 32 KB (i,f all 128 p)
  __shared__ __align__(16) float vot[CL][64];    // 8 KB (v,o own qtr)
  __shared__ float den_part[4][8][2];
  __shared__ float den[CL];
  const int tid = threadIdx.x;
  const int lane = tid & 63, wid = tid >> 6;
  const int blk = blockIdx.x;
  const int b = blk & 7, ch = (blk >> 3) & (NCH - 1), qtr = blk >> 7;
  const int t0 = ch * CL;
  const int p0 = qtr * 32;
  const size_t boff = (size_t)b * TT * HH;
  const float* qg = act + boff;
  const float* kg = act + BTH + boff;
  const float* ifg = act + 2 * BTH + 2 * boff;
  const float* vog = act + 4 * BTH + 2 * boff;

#pragma unroll
  for (int i = 0; i < CL / 16; ++i) {
    const int u = tid + 512 * i;
    const int r = u >> 5, c = (u & 31) * 4;
    *(float4*)&qt[r][c] = *(const float4*)(qg + (size_t)(t0 + r) * HH + c);
    *(float4*)&kt[r][c] = *(const float4*)(kg + (size_t)(t0 + r) * HH + c);
  }
#pragma unroll
  for (int i = 0; i < 4; ++i) {                  // CL x 256 = 2048 f4
    const int u = tid + 512 * i;
    const int r = u >> 6, c = (u & 63) * 4;
    *(float4*)&iff[r][c] =
        *(const float4*)(ifg + (size_t)(t0 + r) * 2 * HH + c);
  }
  {
    const int r = tid >> 4, c = (tid & 15) * 4;
    *(float4*)&vot[r][c] =
        *(const float4*)(vog + (size_t)(t0 + r) * 2 * HH + 2 * p0 + c);
  }
  __syncthreads();

  // ---- den phase: thread = (seg, pd) ----
  {
    const int seg = tid >> 7, pd = tid & 127;
    const size_t cidx = (size_t)b * 128 + pd;
    // register-unrolled summary loads (compile-time indices -> no scratch,
    // loads issue in parallel; compose chain is then pure FMA)
    float av[NCH], bv[NCH];
#pragma unroll
    for (int g = 0; g < NCH; ++g) {
      av[g] = abuf[(size_t)g * 1024 + cidx];
      bv[g] = nbufB[(size_t)g * 1024 + cidx];
    }
    float a8[3], b8[3];
#pragma unroll
    for (int s = 0; s < 3; ++s) {
      const size_t si = (size_t)(ch * 4 + s) * 1024 + cidx;
      a8[s] = segA8[si];
      b8[s] = segB8[si];
    }
    float n = 0.f;
#pragma unroll
    for (int g = 0; g < NCH; ++g)
      if (g < ch) n = fmaf(av[g], n, bv[g]);
#pragma unroll
    for (int s = 0; s < 3; ++s)
      if (s < seg) n = fmaf(a8[s], n, b8[s]);
    // 8 local steps from LDS; prod = OLD n * q (reference semantics)
    float prod[8];
#pragma unroll
    for (int j = 0; j < 8; ++j) {
      const int tl = seg * 8 + j;
      const float iv = iff[tl][2 * pd];
      const float fv = iff[tl][2 * pd + 1];
      prod[j] = n * qt[tl][pd];
      n = fmaf(fv, n, iv * kt[tl][pd]);
    }
    // full-wave reduce (64 p's per wave) -> lane 63
#pragma unroll
    for (int j = 0; j < 8; ++j) {
      float s = prod[j];
      s = dpp_add<0x111>(s);
      s = dpp_add<0x112>(s);
      s = dpp_add<0x114>(s);
      s = dpp_add<0x118>(s);
      s = dpp_add<0x142>(s);
      s = dpp_add<0x143>(s);
      prod[j] = s;
    }
    if (lane == 63) {
#pragma unroll
      for (int j = 0; j < 8; ++j) den_part[seg][j][wid & 1] = prod[j];
    }
  }
  __syncthreads();
  if (tid < CL) {
    const int s_ = tid >> 3, j_ = tid & 7;
    const float d = den_part[s_][j_][0] + den_part[s_][j_][1];
    den[tid] = __builtin_amdgcn_rcpf(fmaxf(fabsf(d), 1.0f));
  }
  __syncthreads();
  {
    int u = tid;                                 // 32 t x 32 pp o-elements
    vot[u >> 5][2 * (u & 31) + 1] *= den[u >> 5];
    u = tid + 512;
    vot[u >> 5][2 * (u & 31) + 1] *= den[u >> 5];
  }
  __syncthreads();

  // ---- replay (round-7 hscan2, gif from iff) ----
  const int pl = lane >> 4, cl = lane & 15;
  const int plocal = wid * 4 + pl;
  const int p = p0 + plocal;

  float C[8];
#pragma unroll
  for (int j = 0; j < 8; ++j) C[j] = 0.f;
  {
    const size_t cb = (size_t)(b * 128 + p) * NCH;
#pragma unroll 1
    for (int g = 0; g < ch; ++g) {
      const float a = abuf[(size_t)g * 1024 + b * 128 + p];
      const float4 b0 = *(const float4*)(cbuf + (cb + g) * 128 + cl * 4);
      const float4 b1 = *(const float4*)(cbuf + (cb + g) * 128 + cl * 4 + 64);
      C[0] = fmaf(a, C[0], b0.x);
      C[1] = fmaf(a, C[1], b0.y);
      C[2] = fmaf(a, C[2], b0.z);
      C[3] = fmaf(a, C[3], b0.w);
      C[4] = fmaf(a, C[4], b1.x);
      C[5] = fmaf(a, C[5], b1.y);
      C[6] = fmaf(a, C[6], b1.z);
      C[7] = fmaf(a, C[7], b1.w);
    }
  }
  float* hbase = hout + boff + p;

#pragma unroll 4
  for (int t = 0; t < CL; ++t) {
    const float2 gif = *(const float2*)&iff[t][2 * p];
    const float2 gvo = *(const float2*)&vot[t][2 * plocal];
    const float4 q0 = *(const float4*)&qt[t][cl * 4];
    const float4 q1 = *(const float4*)&qt[t][cl * 4 + 64];
    const float4 k0 = *(const float4*)&kt[t][cl * 4];
    const float4 k1 = *(const float4*)&kt[t][cl * 4 + 64];
    // h-tilde partial from OLD C
    float s0 = C[0] * q0.x;
    float s1 = C[4] * q1.x;
    s0 = fmaf(C[1], q0.y, s0);
    s1 = fmaf(C[5], q1.y, s1);
    s0 = fmaf(C[2], q0.z, s0);
    s1 = fmaf(C[6], q1.z, s1);
    s0 = fmaf(C[3], q0.w, s0);
    s1 = fmaf(C[7], q1.w, s1);
    float s = s0 + s1;
    // C update
    const float a = gif.x * gvo.x;               // i*v
    const float f = gif.y;
    C[0] = fmaf(f, C[0], a * k0.x);
    C[1] = fmaf(f, C[1], a * k0.y);
    C[2] = fmaf(f, C[2], a * k0.z);
    C[3] = fmaf(f, C[3], a * k0.w);
    C[4] = fmaf(f, C[4], a * k1.x);
    C[5] = fmaf(f, C[5], a * k1.y);
    C[6] = fmaf(f, C[6], a * k1.z);
    C[7] = fmaf(f, C[7], a * k1.w);
    // reduce over the 16-lane row: lane cl==15 holds the full col-sum
    s = dpp_add<0x111>(s);
    s = dpp_add<0x112>(s);
    s = dpp_add<0x114>(s);
    s = dpp_add<0x118>(s);
    if (cl == 15) hbase[(size_t)(t0 + t) * HH] = s * gvo.y;  // o*invden
  }
}

// ---------------------------------------------------------------------------
extern "C" void kernel_launch(void* const* d_in, const int* in_sizes, int n_in,
                              void* d_out, int out_size, void* d_ws,
                              size_t ws_size, hipStream_t stream) {
  (void)in_sizes; (void)n_in; (void)out_size; (void)ws_size;
  const float* x = (const float*)d_in[0];
  float* act = (float*)d_ws;                     // 6 * BTH floats
  float* hbuf = act + 6 * BTH;                   // BTH floats (layer-1 h)
  float* cbuf = act + 7 * BTH;                   // 1024*NCH*128 floats (8 MB)
  float* abuf = cbuf + (size_t)1024 * NCH * 128; // 16K floats
  float* nbufB = abuf + 16384;                   // 16K floats
  float* segA8 = nbufB + 16384;                  // 64K floats
  float* segB8 = segA8 + 65536;                  // 64K floats
  float* Wt = (float*)d_out;                     // [0, 196608)

  WArgs wa;
  for (int j = 0; j < 6; ++j) wa.W[j] = (const float*)d_in[1 + j];
  transpose_w<<<dim3(16, 12), 256, 0, stream>>>(wa, Wt);

  for (int l = 0; l < 2; ++l) {
    BArgs ba;
    for (int j = 0; j < 6; ++j)
      ba.b[j] = (const float*)d_in[7 + j] + (size_t)l * HH;
    const float* wtl = Wt + (size_t)l * 6 * HH * DD;
    const float* xin = (l == 0) ? x : hbuf;
    float* hdst = (l == 0) ? hbuf : (float*)d_out;
    proj_kernel<<<dim3(BT_ / 64, 6), 256, 0, stream>>>(xin, wtl, ba, act);
    cseg2_kernel<<<512, 512, 0, stream>>>(act, cbuf, abuf, nbufB, segA8,
                                          segB8);
    hscan3_kernel<<<512, 512, 0, stream>>>(act, hdst, cbuf, abuf, nbufB,
                                           segA8, segB8);
  }
}